// Round 3
// baseline (12840.541 us; speedup 1.0000x reference)
//
#include <hip/hip_runtime.h>
#include <float.h>
#include <math.h>

#define NB 4
#define NPTS 8192
#define NS 4096
#define MIDC 32
#define OUTC 64
#define CATC 67
#define BN_EPS 1e-5f
#define TOTAL_PTS (NB*NPTS)   // 32768
#define TOTAL_S (NB*NS)       // 16384

// ---------------- stats zero-init (ws is poisoned 0xAA each call) ----------------
__global__ void k_zero(float* __restrict__ stats) {
    for (int i = threadIdx.x; i < 320; i += 256) stats[i] = 0.f;
}

// ---------------- first conv: t1[c][p] = x_in[p] . W1[c] + b1[c] ----------------
__global__ void k_first(const float* __restrict__ xin, const float* __restrict__ W1,
                        const float* __restrict__ b1, float* __restrict__ t1) {
    int p = blockIdx.x * blockDim.x + threadIdx.x;  // 0..32767
    float x = xin[p * 3], y = xin[p * 3 + 1], z = xin[p * 3 + 2];
#pragma unroll
    for (int c = 0; c < MIDC; c++) {
        float v = fmaf(W1[c * 3 + 2], z, fmaf(W1[c * 3 + 1], y, fmaf(W1[c * 3], x, b1[c])));
        t1[c * TOTAL_PTS + p] = v;
    }
}

// ---------------- BN1 stats: one block per channel ----------------
__global__ void k_stats1(const float* __restrict__ t1, float* __restrict__ stats) {
    int c = blockIdx.x, tid = threadIdx.x;
    float s = 0.f, ss = 0.f;
    for (int i = tid; i < TOTAL_PTS; i += 256) {
        float v = t1[c * TOTAL_PTS + i];
        s += v; ss = fmaf(v, v, ss);
    }
#pragma unroll
    for (int off = 32; off; off >>= 1) { s += __shfl_down(s, off); ss += __shfl_down(ss, off); }
    __shared__ float ls[4], lss[4];
    int w = tid >> 6, lane = tid & 63;
    if (lane == 0) { ls[w] = s; lss[w] = ss; }
    __syncthreads();
    if (tid == 0) {
        s = ls[0] + ls[1] + ls[2] + ls[3];
        ss = lss[0] + lss[1] + lss[2] + lss[3];
        float m = s / (float)TOTAL_PTS;
        float var = ss / (float)TOTAL_PTS - m * m;
        stats[c] = m;
        stats[32 + c] = rsqrtf(var + BN_EPS);
    }
}

// ---------------- BN1+ReLU then second conv: feat[p][o] ----------------
__global__ void __launch_bounds__(256) k_feat(const float* __restrict__ t1, const float* __restrict__ stats,
                                              const float* __restrict__ g1, const float* __restrict__ be1,
                                              const float* __restrict__ W2, const float* __restrict__ b2,
                                              float* __restrict__ feat) {
    __shared__ float W2s[OUTC * MIDC];
    for (int i = threadIdx.x; i < OUTC * MIDC; i += 256) W2s[i] = W2[i];
    __syncthreads();
    int p = blockIdx.x * blockDim.x + threadIdx.x;
    float h[MIDC];
#pragma unroll
    for (int c = 0; c < MIDC; c++) {
        float v = t1[c * TOTAL_PTS + p];
        v = fmaf((v - stats[c]) * stats[32 + c], g1[c], be1[c]);
        h[c] = fmaxf(v, 0.f);
    }
#pragma unroll 4
    for (int o = 0; o < OUTC; o++) {
        float a = b2[o];
#pragma unroll
        for (int c = 0; c < MIDC; c++) a = fmaf(W2s[o * MIDC + c], h[c], a);
        feat[p * OUTC + o] = a;
    }
}

// ---------------- farthest point sampling (fp64 distances): 1 block per batch ----------------
__global__ void __launch_bounds__(1024) k_fps(const float* __restrict__ xin, int* __restrict__ fidx) {
    const int b = blockIdx.x;
    const int tid = threadIdx.x;
    const int lane = tid & 63, w = tid >> 6;
    const float* xb = xin + (size_t)b * NPTS * 3;
    float px[8], py[8], pz[8];
    double dist[8];
#pragma unroll
    for (int j = 0; j < 8; j++) {
        int p = tid + (j << 10);
        px[j] = xb[p * 3]; py[j] = xb[p * 3 + 1]; pz[j] = xb[p * 3 + 2];
        dist[j] = 1e30;
    }
    __shared__ double swd[16];
    __shared__ float swx[16], swy[16], swz[16], scc[3];
    __shared__ int swi[16];
    if (tid == 0) { scc[0] = xb[0]; scc[1] = xb[1]; scc[2] = xb[2]; fidx[b * NS] = 0; }
    __syncthreads();
    for (int t = 1; t < NS; t++) {
        double cx = (double)scc[0], cy = (double)scc[1], cz = (double)scc[2];
        double bd = -1.0;
        float bx = 0.f, by = 0.f, bz = 0.f;
        int bi = 0x7fffffff;
#pragma unroll
        for (int j = 0; j < 8; j++) {
            double dx = (double)px[j] - cx, dy = (double)py[j] - cy, dz = (double)pz[j] - cz;
            double d = fma(dx, dx, fma(dy, dy, dz * dz));
            double nd = fmin(dist[j], d);
            dist[j] = nd;
            if (nd > bd) { bd = nd; bi = tid + (j << 10); bx = px[j]; by = py[j]; bz = pz[j]; }
        }
#pragma unroll
        for (int off = 32; off; off >>= 1) {
            double od = __shfl_xor(bd, off); int oi = __shfl_xor(bi, off);
            float ox = __shfl_xor(bx, off), oy = __shfl_xor(by, off), oz = __shfl_xor(bz, off);
            if (od > bd || (od == bd && oi < bi)) { bd = od; bi = oi; bx = ox; by = oy; bz = oz; }
        }
        if (lane == 0) { swd[w] = bd; swi[w] = bi; swx[w] = bx; swy[w] = by; swz[w] = bz; }
        __syncthreads();
        if (w == 0) {
            double d2 = (lane < 16) ? swd[lane] : -1.0;
            int i2 = (lane < 16) ? swi[lane] : 0x7fffffff;
            float x2 = (lane < 16) ? swx[lane] : 0.f;
            float y2 = (lane < 16) ? swy[lane] : 0.f;
            float z2 = (lane < 16) ? swz[lane] : 0.f;
#pragma unroll
            for (int off = 8; off; off >>= 1) {
                double od = __shfl_xor(d2, off); int oi = __shfl_xor(i2, off);
                float ox = __shfl_xor(x2, off), oy = __shfl_xor(y2, off), oz = __shfl_xor(z2, off);
                if (od > d2 || (od == d2 && oi < i2)) { d2 = od; i2 = oi; x2 = ox; y2 = oy; z2 = oz; }
            }
            if (lane == 0) { scc[0] = x2; scc[1] = y2; scc[2] = z2; fidx[b * NS + t] = i2; }
        }
        __syncthreads();
    }
}

// ---------------- brute-force kNN top-16 (fp64 direct-form distances) ----------------
#define KT 2048
__global__ void __launch_bounds__(256) k_knn(const float* __restrict__ xin, const int* __restrict__ fidx,
                                             int* __restrict__ knn) {
    __shared__ float sx[KT], sy[KT], sz[KT];
    int blk = blockIdx.x;
    int b = blk >> 4;
    int s = ((blk & 15) << 8) + threadIdx.x;
    const float* xb = xin + (size_t)b * NPTS * 3;
    int qi = fidx[b * NS + s];
    double qx = (double)xb[qi * 3], qy = (double)xb[qi * 3 + 1], qz = (double)xb[qi * 3 + 2];
    double kd[16]; int ki[16];
#pragma unroll
    for (int k = 0; k < 16; k++) { kd[k] = 1e300; ki[k] = -1; }
    for (int tile = 0; tile < NPTS / KT; tile++) {
        for (int m = threadIdx.x; m < KT; m += 256) {
            int gj = tile * KT + m;
            sx[m] = xb[gj * 3]; sy[m] = xb[gj * 3 + 1]; sz[m] = xb[gj * 3 + 2];
        }
        __syncthreads();
        for (int m = 0; m < KT; m++) {
            double dx = qx - (double)sx[m];
            double dy = qy - (double)sy[m];
            double dz = qz - (double)sz[m];
            double d = fma(dx, dx, fma(dy, dy, dz * dz));
            if (d < kd[15]) {
                kd[15] = d; ki[15] = tile * KT + m;
#pragma unroll
                for (int q2 = 15; q2 > 0; q2--) {
                    if (kd[q2] < kd[q2 - 1]) {
                        double td = kd[q2]; kd[q2] = kd[q2 - 1]; kd[q2 - 1] = td;
                        int ti = ki[q2]; ki[q2] = ki[q2 - 1]; ki[q2 - 1] = ti;
                    } else break;
                }
            }
        }
        __syncthreads();
    }
    int gq = b * NS + s;
#pragma unroll
    for (int k = 0; k < 16; k++) knn[gq * 16 + k] = ki[k];
}

// ---------------- gather + maxpool(67) + conv3 (wave per point) ----------------
__global__ void __launch_bounds__(256) k_group(const float* __restrict__ xin, const float* __restrict__ feat,
                                               const int* __restrict__ fidx, const int* __restrict__ knn,
                                               const float* __restrict__ W3, const float* __restrict__ b3,
                                               float* __restrict__ y3, float* __restrict__ stats) {
    __shared__ float W3s[OUTC * CATC];
    __shared__ float x67[4][68];
    __shared__ float lsum[64], lsq[64];
    int tid = threadIdx.x, w = tid >> 6, lane = tid & 63;
    for (int i = tid; i < OUTC * CATC; i += 256) W3s[i] = W3[i];
    if (tid < 64) { lsum[tid] = 0.f; lsq[tid] = 0.f; }
    __syncthreads();
    float psum = 0.f, psq = 0.f;
    int p0 = blockIdx.x * 64 + w * 16;
    for (int it = 0; it < 16; it++) {
        int p = p0 + it;
        int b = p >> 12;
        int myidx = knn[p * 16 + (lane & 15)];
        int nbk[16];
#pragma unroll
        for (int k = 0; k < 16; k++) nbk[k] = __shfl(myidx, k);
        float m = -FLT_MAX;
#pragma unroll
        for (int k = 0; k < 16; k++) m = fmaxf(m, feat[(size_t)(b * NPTS + nbk[k]) * OUTC + lane]);
        x67[w][3 + lane] = m;
        if (lane < 3) {
            int ci = fidx[p];
            float cc = xin[(size_t)(b * NPTS + ci) * 3 + lane];
            float mg = -FLT_MAX;
#pragma unroll
            for (int k = 0; k < 16; k++) mg = fmaxf(mg, xin[(size_t)(b * NPTS + nbk[k]) * 3 + lane] - cc);
            x67[w][lane] = mg;
        }
        __syncthreads();
        float acc = b3[lane];
#pragma unroll
        for (int c = 0; c < CATC; c++) acc = fmaf(W3s[lane * CATC + c], x67[w][c], acc);
        y3[(size_t)p * OUTC + lane] = acc;
        psum += acc; psq = fmaf(acc, acc, psq);
        __syncthreads();
    }
    atomicAdd(&lsum[lane], psum);
    atomicAdd(&lsq[lane], psq);
    __syncthreads();
    if (tid < 64) { atomicAdd(&stats[64 + tid], lsum[tid]); atomicAdd(&stats[128 + tid], lsq[tid]); }
}

// ---------------- BN2 finalize ----------------
__global__ void k_stats2(float* __restrict__ stats) {
    int c = threadIdx.x;  // 64
    float m = stats[64 + c] / (float)TOTAL_S;
    float var = stats[128 + c] / (float)TOTAL_S - m * m;
    stats[192 + c] = m;
    stats[256 + c] = rsqrtf(var + BN_EPS);
}

// ---------------- BN2 + ReLU in place on y3 ----------------
__global__ void k_bnrelu2(float* __restrict__ y3, const float* __restrict__ stats,
                          const float* __restrict__ g2, const float* __restrict__ be2) {
    int i = blockIdx.x * blockDim.x + threadIdx.x;
    int c = i & 63;
    float v = y3[i];
    v = fmaf((v - stats[192 + c]) * stats[256 + c], g2[c], be2[c]);
    y3[i] = fmaxf(v, 0.f);
}

// ---------------- final conv: out = y3' @ W4^T + b4 ----------------
__global__ void __launch_bounds__(256) k_last(const float* __restrict__ y3, const float* __restrict__ W4,
                                              const float* __restrict__ b4, float* __restrict__ out) {
    __shared__ float W4t[OUTC * OUTC];
    for (int i = threadIdx.x; i < OUTC * OUTC; i += 256) W4t[(i & 63) * 64 + (i >> 6)] = W4[i];
    __syncthreads();
    int t = blockIdx.x * 256 + threadIdx.x;
    int p = t >> 6, o = t & 63;
    const float* yp = y3 + (size_t)p * OUTC;
    float acc = b4[o];
#pragma unroll
    for (int c = 0; c < OUTC; c++) acc = fmaf(W4t[c * 64 + o], yp[c], acc);
    out[t] = acc;
}

extern "C" void kernel_launch(void* const* d_in, const int* in_sizes, int n_in,
                              void* d_out, int out_size, void* d_ws, size_t ws_size,
                              hipStream_t stream) {
    const float* xin = (const float*)d_in[0];
    const float* W1  = (const float*)d_in[1];
    const float* b1  = (const float*)d_in[2];
    const float* g1  = (const float*)d_in[3];
    const float* be1 = (const float*)d_in[4];
    const float* W2  = (const float*)d_in[5];
    const float* b2  = (const float*)d_in[6];
    const float* W3  = (const float*)d_in[7];
    const float* b3  = (const float*)d_in[8];
    const float* g2  = (const float*)d_in[9];
    const float* be2 = (const float*)d_in[10];
    const float* W4  = (const float*)d_in[11];
    const float* b4  = (const float*)d_in[12];
    float* out = (float*)d_out;

    float* ws = (float*)d_ws;
    float* t1   = ws;                                       // 32*32768   = 1,048,576 f
    float* feat = t1 + (size_t)MIDC * TOTAL_PTS;            // 32768*64   = 2,097,152 f
    int*   fidx = (int*)(feat + (size_t)TOTAL_PTS * OUTC);  // 16384 i
    int*   knn  = fidx + TOTAL_S;                           // 16384*16   = 262,144 i
    float* y3   = (float*)(knn + (size_t)TOTAL_S * 16);     // 16384*64   = 1,048,576 f
    float* stats = y3 + (size_t)TOTAL_S * OUTC;             // 320 f

    k_zero<<<1, 256, 0, stream>>>(stats);
    k_first<<<TOTAL_PTS / 256, 256, 0, stream>>>(xin, W1, b1, t1);
    k_stats1<<<MIDC, 256, 0, stream>>>(t1, stats);
    k_feat<<<TOTAL_PTS / 256, 256, 0, stream>>>(t1, stats, g1, be1, W2, b2, feat);
    k_fps<<<NB, 1024, 0, stream>>>(xin, fidx);
    k_knn<<<NB * (NS / 256), 256, 0, stream>>>(xin, fidx, knn);
    k_group<<<TOTAL_S / 64, 256, 0, stream>>>(xin, feat, fidx, knn, W3, b3, y3, stats);
    k_stats2<<<1, 64, 0, stream>>>(stats);
    k_bnrelu2<<<TOTAL_S * OUTC / 256, 256, 0, stream>>>(y3, stats, g2, be2);
    k_last<<<TOTAL_S * OUTC / 256, 256, 0, stream>>>(y3, W4, b4, out);
}

// Round 4
// 6698.149 us; speedup vs baseline: 1.9170x; 1.9170x over previous
//
#include <hip/hip_runtime.h>
#include <float.h>
#include <math.h>

#define NB 4
#define NPTS 8192
#define NS 4096
#define MIDC 32
#define OUTC 64
#define CATC 67
#define BN_EPS 1e-5f
#define TOTAL_PTS (NB*NPTS)   // 32768
#define TOTAL_S (NB*NS)       // 16384

// Packed selection key: for non-negative doubles, the IEEE754 bit pattern is
// order-isomorphic to the value. We truncate the low 13 mantissa bits
// (2^-39 rel ≈ 2e-12 noise vs ~1e-4 boundary gaps) and store a 13-bit index
// there, making (dist, idx) lexicographic compare a single f64 compare.

// ---------------- stats zero-init (ws is poisoned 0xAA each call) ----------------
__global__ void k_zero(float* __restrict__ stats) {
    for (int i = threadIdx.x; i < 320; i += 256) stats[i] = 0.f;
}

// ---------------- first conv: t1[c][p] = x_in[p] . W1[c] + b1[c] ----------------
__global__ void k_first(const float* __restrict__ xin, const float* __restrict__ W1,
                        const float* __restrict__ b1, float* __restrict__ t1) {
    int p = blockIdx.x * blockDim.x + threadIdx.x;  // 0..32767
    float x = xin[p * 3], y = xin[p * 3 + 1], z = xin[p * 3 + 2];
#pragma unroll
    for (int c = 0; c < MIDC; c++) {
        float v = fmaf(W1[c * 3 + 2], z, fmaf(W1[c * 3 + 1], y, fmaf(W1[c * 3], x, b1[c])));
        t1[c * TOTAL_PTS + p] = v;
    }
}

// ---------------- BN1 stats: one block per channel ----------------
__global__ void k_stats1(const float* __restrict__ t1, float* __restrict__ stats) {
    int c = blockIdx.x, tid = threadIdx.x;
    float s = 0.f, ss = 0.f;
    for (int i = tid; i < TOTAL_PTS; i += 256) {
        float v = t1[c * TOTAL_PTS + i];
        s += v; ss = fmaf(v, v, ss);
    }
#pragma unroll
    for (int off = 32; off; off >>= 1) { s += __shfl_down(s, off); ss += __shfl_down(ss, off); }
    __shared__ float ls[4], lss[4];
    int w = tid >> 6, lane = tid & 63;
    if (lane == 0) { ls[w] = s; lss[w] = ss; }
    __syncthreads();
    if (tid == 0) {
        s = ls[0] + ls[1] + ls[2] + ls[3];
        ss = lss[0] + lss[1] + lss[2] + lss[3];
        float m = s / (float)TOTAL_PTS;
        float var = ss / (float)TOTAL_PTS - m * m;
        stats[c] = m;
        stats[32 + c] = rsqrtf(var + BN_EPS);
    }
}

// ---------------- BN1+ReLU then second conv: feat[p][o] ----------------
__global__ void __launch_bounds__(256) k_feat(const float* __restrict__ t1, const float* __restrict__ stats,
                                              const float* __restrict__ g1, const float* __restrict__ be1,
                                              const float* __restrict__ W2, const float* __restrict__ b2,
                                              float* __restrict__ feat) {
    __shared__ float W2s[OUTC * MIDC];
    for (int i = threadIdx.x; i < OUTC * MIDC; i += 256) W2s[i] = W2[i];
    __syncthreads();
    int p = blockIdx.x * blockDim.x + threadIdx.x;
    float h[MIDC];
#pragma unroll
    for (int c = 0; c < MIDC; c++) {
        float v = t1[c * TOTAL_PTS + p];
        v = fmaf((v - stats[c]) * stats[32 + c], g1[c], be1[c]);
        h[c] = fmaxf(v, 0.f);
    }
#pragma unroll 4
    for (int o = 0; o < OUTC; o++) {
        float a = b2[o];
#pragma unroll
        for (int c = 0; c < MIDC; c++) a = fmaf(W2s[o * MIDC + c], h[c], a);
        feat[p * OUTC + o] = a;
    }
}

// ---------------- farthest point sampling (fp64, packed-key argmax) ----------------
// key = (dist bits & ~0x1FFF) | (8191 - point_idx): f64-max == (max dist, min idx).
__global__ void __launch_bounds__(1024) k_fps(const float* __restrict__ xin, int* __restrict__ fidx) {
    const int b = blockIdx.x;
    const int tid = threadIdx.x;
    const int lane = tid & 63;
    const float* xb = xin + (size_t)b * NPTS * 3;
    double px[8], py[8], pz[8], dist[8];
#pragma unroll
    for (int j = 0; j < 8; j++) {
        int p = tid + (j << 10);
        px[j] = (double)xb[p * 3]; py[j] = (double)xb[p * 3 + 1]; pz[j] = (double)xb[p * 3 + 2];
        dist[j] = 1e30;
    }
    __shared__ double scc[3];
    __shared__ unsigned long long gkey[2];
    if (tid == 0) {
        scc[0] = px[0]; scc[1] = py[0]; scc[2] = pz[0];   // point 0 lives in tid 0, j 0
        fidx[b * NS] = 0;
        gkey[0] = 0ULL; gkey[1] = 0ULL;
    }
    __syncthreads();
    for (int t = 1; t < NS; t++) {
        double cx = scc[0], cy = scc[1], cz = scc[2];
        double wmax = -1.0;
#pragma unroll
        for (int j = 0; j < 8; j++) {
            double dx = px[j] - cx, dy = py[j] - cy, dz = pz[j] - cz;
            double d = fma(dx, dx, fma(dy, dy, dz * dz));
            double nd = fmin(dist[j], d);
            dist[j] = nd;
            unsigned long long kb = (__double_as_longlong(nd) & 0xFFFFFFFFFFFFE000ULL)
                                  | (unsigned long long)(8191 - (tid + (j << 10)));
            wmax = fmax(wmax, __longlong_as_double(kb));
        }
#pragma unroll
        for (int off = 32; off; off >>= 1)
            wmax = fmax(wmax, __shfl_xor(wmax, off));
        if (lane == 0)
            atomicMax(&gkey[t & 1], (unsigned long long)__double_as_longlong(wmax));
        __syncthreads();
        int idx = 8191 - (int)(gkey[t & 1] & 0x1FFFULL);
#pragma unroll
        for (int j = 0; j < 8; j++) {
            if (tid + (j << 10) == idx) {
                scc[0] = px[j]; scc[1] = py[j]; scc[2] = pz[j];
                fidx[b * NS + t] = idx;
            }
        }
        if (tid == 0) gkey[(t + 1) & 1] = 0ULL;   // reset the other slot for the next step
        __syncthreads();
    }
}

// ---------------- brute-force kNN top-16, packed keys, 4-way ref split ----------------
// Block: 64 queries x 4 parts (part == wave). Each part scans 2048 refs keeping a
// sorted top-16 of packed keys in 16 scalar registers (no arrays -> no scratch).
#define KT2 1024
__global__ void __launch_bounds__(256) k_knn(const float* __restrict__ xin, const int* __restrict__ fidx,
                                             int* __restrict__ knn) {
    __shared__ double sxd[KT2], syd[KT2], szd[KT2];     // 24 KB
    __shared__ double mk[4][16][64];                     // 32 KB: [part][rank][query]
    int tid = threadIdx.x;
    int part = tid >> 6;
    int ql = tid & 63;
    int gq = blockIdx.x * 64 + ql;
    int b = gq >> 12;
    const float* xb = xin + (size_t)b * NPTS * 3;
    int qi = fidx[gq];
    double qx = (double)xb[qi * 3], qy = (double)xb[qi * 3 + 1], qz = (double)xb[qi * 3 + 2];
    double kd0 = DBL_MAX, kd1 = DBL_MAX, kd2 = DBL_MAX, kd3 = DBL_MAX,
           kd4 = DBL_MAX, kd5 = DBL_MAX, kd6 = DBL_MAX, kd7 = DBL_MAX,
           kd8 = DBL_MAX, kd9 = DBL_MAX, kd10 = DBL_MAX, kd11 = DBL_MAX,
           kd12 = DBL_MAX, kd13 = DBL_MAX, kd14 = DBL_MAX, kd15 = DBL_MAX;
    for (int tile = 0; tile < NPTS / KT2; tile++) {
        for (int m = tid; m < KT2; m += 256) {
            int gj = tile * KT2 + m;
            sxd[m] = (double)xb[gj * 3];
            syd[m] = (double)xb[gj * 3 + 1];
            szd[m] = (double)xb[gj * 3 + 2];
        }
        __syncthreads();
        int base = part * (KT2 / 4);
        for (int m = 0; m < KT2 / 4; m++) {
            int li = base + m;
            double dx = qx - sxd[li], dy = qy - syd[li], dz = qz - szd[li];
            double d = fma(dx, dx, fma(dy, dy, dz * dz));
            double key = __longlong_as_double(
                (__double_as_longlong(d) & 0xFFFFFFFFFFFFE000ULL)
                | (unsigned long long)(tile * KT2 + li));
            if (key < kd15) {
                // branchless sorted shift-insert (top-down uses pre-update neighbors)
                kd15 = fmax(kd14, fmin(kd15, key)); kd14 = fmax(kd13, fmin(kd14, key));
                kd13 = fmax(kd12, fmin(kd13, key)); kd12 = fmax(kd11, fmin(kd12, key));
                kd11 = fmax(kd10, fmin(kd11, key)); kd10 = fmax(kd9,  fmin(kd10, key));
                kd9  = fmax(kd8,  fmin(kd9,  key)); kd8  = fmax(kd7,  fmin(kd8,  key));
                kd7  = fmax(kd6,  fmin(kd7,  key)); kd6  = fmax(kd5,  fmin(kd6,  key));
                kd5  = fmax(kd4,  fmin(kd5,  key)); kd4  = fmax(kd3,  fmin(kd4,  key));
                kd3  = fmax(kd2,  fmin(kd3,  key)); kd2  = fmax(kd1,  fmin(kd2,  key));
                kd1  = fmax(kd0,  fmin(kd1,  key)); kd0  = fmin(kd0,  key);
            }
        }
        __syncthreads();
    }
    mk[part][0][ql] = kd0;  mk[part][1][ql] = kd1;  mk[part][2][ql] = kd2;  mk[part][3][ql] = kd3;
    mk[part][4][ql] = kd4;  mk[part][5][ql] = kd5;  mk[part][6][ql] = kd6;  mk[part][7][ql] = kd7;
    mk[part][8][ql] = kd8;  mk[part][9][ql] = kd9;  mk[part][10][ql] = kd10; mk[part][11][ql] = kd11;
    mk[part][12][ql] = kd12; mk[part][13][ql] = kd13; mk[part][14][ql] = kd14; mk[part][15][ql] = kd15;
    __syncthreads();
    if (tid < 64) {
        // 4-way merge of sorted lists; keys are globally unique (index in low bits)
        int i0 = 0, i1 = 0, i2 = 0, i3 = 0;
        double h0 = mk[0][0][tid], h1 = mk[1][0][tid], h2 = mk[2][0][tid], h3 = mk[3][0][tid];
        int* outp = knn + (size_t)(blockIdx.x * 64 + tid) * 16;
#pragma unroll
        for (int k = 0; k < 16; k++) {
            double mm = fmin(fmin(h0, h1), fmin(h2, h3));
            outp[k] = (int)(__double_as_longlong(mm) & 0x1FFFULL);
            if (mm == h0)      { i0++; h0 = (i0 < 16) ? mk[0][i0][tid] : DBL_MAX; }
            else if (mm == h1) { i1++; h1 = (i1 < 16) ? mk[1][i1][tid] : DBL_MAX; }
            else if (mm == h2) { i2++; h2 = (i2 < 16) ? mk[2][i2][tid] : DBL_MAX; }
            else               { i3++; h3 = (i3 < 16) ? mk[3][i3][tid] : DBL_MAX; }
        }
    }
}

// ---------------- gather + maxpool(67) + conv3 (wave per point) ----------------
__global__ void __launch_bounds__(256) k_group(const float* __restrict__ xin, const float* __restrict__ feat,
                                               const int* __restrict__ fidx, const int* __restrict__ knn,
                                               const float* __restrict__ W3, const float* __restrict__ b3,
                                               float* __restrict__ y3, float* __restrict__ stats) {
    __shared__ float W3s[OUTC * CATC];
    __shared__ float x67[4][68];
    __shared__ float lsum[64], lsq[64];
    int tid = threadIdx.x, w = tid >> 6, lane = tid & 63;
    for (int i = tid; i < OUTC * CATC; i += 256) W3s[i] = W3[i];
    if (tid < 64) { lsum[tid] = 0.f; lsq[tid] = 0.f; }
    __syncthreads();
    float psum = 0.f, psq = 0.f;
    int p0 = blockIdx.x * 64 + w * 16;
    for (int it = 0; it < 16; it++) {
        int p = p0 + it;
        int b = p >> 12;
        int myidx = knn[p * 16 + (lane & 15)];
        int nbk[16];
#pragma unroll
        for (int k = 0; k < 16; k++) nbk[k] = __shfl(myidx, k);
        float m = -FLT_MAX;
#pragma unroll
        for (int k = 0; k < 16; k++) m = fmaxf(m, feat[(size_t)(b * NPTS + nbk[k]) * OUTC + lane]);
        x67[w][3 + lane] = m;
        if (lane < 3) {
            int ci = fidx[p];
            float cc = xin[(size_t)(b * NPTS + ci) * 3 + lane];
            float mg = -FLT_MAX;
#pragma unroll
            for (int k = 0; k < 16; k++) mg = fmaxf(mg, xin[(size_t)(b * NPTS + nbk[k]) * 3 + lane] - cc);
            x67[w][lane] = mg;
        }
        __syncthreads();
        float acc = b3[lane];
#pragma unroll
        for (int c = 0; c < CATC; c++) acc = fmaf(W3s[lane * CATC + c], x67[w][c], acc);
        y3[(size_t)p * OUTC + lane] = acc;
        psum += acc; psq = fmaf(acc, acc, psq);
        __syncthreads();
    }
    atomicAdd(&lsum[lane], psum);
    atomicAdd(&lsq[lane], psq);
    __syncthreads();
    if (tid < 64) { atomicAdd(&stats[64 + tid], lsum[tid]); atomicAdd(&stats[128 + tid], lsq[tid]); }
}

// ---------------- BN2 finalize ----------------
__global__ void k_stats2(float* __restrict__ stats) {
    int c = threadIdx.x;  // 64
    float m = stats[64 + c] / (float)TOTAL_S;
    float var = stats[128 + c] / (float)TOTAL_S - m * m;
    stats[192 + c] = m;
    stats[256 + c] = rsqrtf(var + BN_EPS);
}

// ---------------- BN2 + ReLU in place on y3 ----------------
__global__ void k_bnrelu2(float* __restrict__ y3, const float* __restrict__ stats,
                          const float* __restrict__ g2, const float* __restrict__ be2) {
    int i = blockIdx.x * blockDim.x + threadIdx.x;
    int c = i & 63;
    float v = y3[i];
    v = fmaf((v - stats[192 + c]) * stats[256 + c], g2[c], be2[c]);
    y3[i] = fmaxf(v, 0.f);
}

// ---------------- final conv: out = y3' @ W4^T + b4 ----------------
__global__ void __launch_bounds__(256) k_last(const float* __restrict__ y3, const float* __restrict__ W4,
                                              const float* __restrict__ b4, float* __restrict__ out) {
    __shared__ float W4t[OUTC * OUTC];
    for (int i = threadIdx.x; i < OUTC * OUTC; i += 256) W4t[(i & 63) * 64 + (i >> 6)] = W4[i];
    __syncthreads();
    int t = blockIdx.x * 256 + threadIdx.x;
    int p = t >> 6, o = t & 63;
    const float* yp = y3 + (size_t)p * OUTC;
    float acc = b4[o];
#pragma unroll
    for (int c = 0; c < OUTC; c++) acc = fmaf(W4t[c * 64 + o], yp[c], acc);
    out[t] = acc;
}

extern "C" void kernel_launch(void* const* d_in, const int* in_sizes, int n_in,
                              void* d_out, int out_size, void* d_ws, size_t ws_size,
                              hipStream_t stream) {
    const float* xin = (const float*)d_in[0];
    const float* W1  = (const float*)d_in[1];
    const float* b1  = (const float*)d_in[2];
    const float* g1  = (const float*)d_in[3];
    const float* be1 = (const float*)d_in[4];
    const float* W2  = (const float*)d_in[5];
    const float* b2  = (const float*)d_in[6];
    const float* W3  = (const float*)d_in[7];
    const float* b3  = (const float*)d_in[8];
    const float* g2  = (const float*)d_in[9];
    const float* be2 = (const float*)d_in[10];
    const float* W4  = (const float*)d_in[11];
    const float* b4  = (const float*)d_in[12];
    float* out = (float*)d_out;

    float* ws = (float*)d_ws;
    float* t1   = ws;                                       // 32*32768   = 1,048,576 f
    float* feat = t1 + (size_t)MIDC * TOTAL_PTS;            // 32768*64   = 2,097,152 f
    int*   fidx = (int*)(feat + (size_t)TOTAL_PTS * OUTC);  // 16384 i
    int*   knn  = fidx + TOTAL_S;                           // 16384*16   = 262,144 i
    float* y3   = (float*)(knn + (size_t)TOTAL_S * 16);     // 16384*64   = 1,048,576 f
    float* stats = y3 + (size_t)TOTAL_S * OUTC;             // 320 f

    k_zero<<<1, 256, 0, stream>>>(stats);
    k_first<<<TOTAL_PTS / 256, 256, 0, stream>>>(xin, W1, b1, t1);
    k_stats1<<<MIDC, 256, 0, stream>>>(t1, stats);
    k_feat<<<TOTAL_PTS / 256, 256, 0, stream>>>(t1, stats, g1, be1, W2, b2, feat);
    k_fps<<<NB, 1024, 0, stream>>>(xin, fidx);
    k_knn<<<TOTAL_S / 64, 256, 0, stream>>>(xin, fidx, knn);
    k_group<<<TOTAL_S / 64, 256, 0, stream>>>(xin, feat, fidx, knn, W3, b3, y3, stats);
    k_stats2<<<1, 64, 0, stream>>>(stats);
    k_bnrelu2<<<TOTAL_S * OUTC / 256, 256, 0, stream>>>(y3, stats, g2, be2);
    k_last<<<TOTAL_S * OUTC / 256, 256, 0, stream>>>(y3, W4, b4, out);
}

// Round 5
// 5344.280 us; speedup vs baseline: 2.4027x; 1.2533x over previous
//
#include <hip/hip_runtime.h>
#include <float.h>
#include <math.h>

#define NB 4
#define NPTS 8192
#define NS 4096
#define MIDC 32
#define OUTC 64
#define CATC 67
#define BN_EPS 1e-5f
#define TOTAL_PTS (NB*NPTS)   // 32768
#define TOTAL_S (NB*NS)       // 16384

// Packed selection key: for non-negative doubles, the IEEE754 bit pattern is
// order-isomorphic to the value. We truncate the low 13 mantissa bits
// (2^-39 rel ≈ 2e-12 noise vs ~1e-4 boundary gaps) and store a 13-bit
// (reversed) index there, making (dist, idx) lexicographic compare a single
// f64 compare. Packing is order-preserving per point, so dist[] can be
// stored as keys and min-updated with fmin directly.

// ---------------- stats zero-init (ws is poisoned 0xAA each call) ----------------
__global__ void k_zero(float* __restrict__ stats) {
    for (int i = threadIdx.x; i < 320; i += 256) stats[i] = 0.f;
}

// ---------------- first conv: t1[c][p] = x_in[p] . W1[c] + b1[c] ----------------
__global__ void k_first(const float* __restrict__ xin, const float* __restrict__ W1,
                        const float* __restrict__ b1, float* __restrict__ t1) {
    int p = blockIdx.x * blockDim.x + threadIdx.x;  // 0..32767
    float x = xin[p * 3], y = xin[p * 3 + 1], z = xin[p * 3 + 2];
#pragma unroll
    for (int c = 0; c < MIDC; c++) {
        float v = fmaf(W1[c * 3 + 2], z, fmaf(W1[c * 3 + 1], y, fmaf(W1[c * 3], x, b1[c])));
        t1[c * TOTAL_PTS + p] = v;
    }
}

// ---------------- BN1 stats: one block per channel ----------------
__global__ void k_stats1(const float* __restrict__ t1, float* __restrict__ stats) {
    int c = blockIdx.x, tid = threadIdx.x;
    float s = 0.f, ss = 0.f;
    for (int i = tid; i < TOTAL_PTS; i += 256) {
        float v = t1[c * TOTAL_PTS + i];
        s += v; ss = fmaf(v, v, ss);
    }
#pragma unroll
    for (int off = 32; off; off >>= 1) { s += __shfl_down(s, off); ss += __shfl_down(ss, off); }
    __shared__ float ls[4], lss[4];
    int w = tid >> 6, lane = tid & 63;
    if (lane == 0) { ls[w] = s; lss[w] = ss; }
    __syncthreads();
    if (tid == 0) {
        s = ls[0] + ls[1] + ls[2] + ls[3];
        ss = lss[0] + lss[1] + lss[2] + lss[3];
        float m = s / (float)TOTAL_PTS;
        float var = ss / (float)TOTAL_PTS - m * m;
        stats[c] = m;
        stats[32 + c] = rsqrtf(var + BN_EPS);
    }
}

// ---------------- BN1+ReLU then second conv: feat[p][o] ----------------
__global__ void __launch_bounds__(256) k_feat(const float* __restrict__ t1, const float* __restrict__ stats,
                                              const float* __restrict__ g1, const float* __restrict__ be1,
                                              const float* __restrict__ W2, const float* __restrict__ b2,
                                              float* __restrict__ feat) {
    __shared__ float W2s[OUTC * MIDC];
    for (int i = threadIdx.x; i < OUTC * MIDC; i += 256) W2s[i] = W2[i];
    __syncthreads();
    int p = blockIdx.x * blockDim.x + threadIdx.x;
    float h[MIDC];
#pragma unroll
    for (int c = 0; c < MIDC; c++) {
        float v = t1[c * TOTAL_PTS + p];
        v = fmaf((v - stats[c]) * stats[32 + c], g1[c], be1[c]);
        h[c] = fmaxf(v, 0.f);
    }
#pragma unroll 4
    for (int o = 0; o < OUTC; o++) {
        float a = b2[o];
#pragma unroll
        for (int c = 0; c < MIDC; c++) a = fmaf(W2s[o * MIDC + c], h[c], a);
        feat[p * OUTC + o] = a;
    }
}

// ---------------- farthest point sampling (fp64, packed-key, 1 barrier/step) ----------------
// 512 threads x 16 pts. Per step: dist min-update on packed keys -> wave
// butterfly max -> lane0 writes swd[buf][wave] -> barrier -> all threads
// fmax 8 values, extract idx, scalar-load centroid from global (L1 bcast).
__global__ void __launch_bounds__(512) k_fps(const float* __restrict__ xin, int* __restrict__ fidx) {
    const int b = blockIdx.x;
    const int tid = threadIdx.x;
    const int lane = tid & 63, w = tid >> 6;  // 8 waves
    const float* xb = xin + (size_t)b * NPTS * 3;
    double px[16], py[16], pz[16], dk[16];
    unsigned int rid[16];
#pragma unroll
    for (int j = 0; j < 16; j++) {
        int p = tid + (j << 9);
        px[j] = (double)xb[p * 3];
        py[j] = (double)xb[p * 3 + 1];
        pz[j] = (double)xb[p * 3 + 2];
        rid[j] = (unsigned int)(8191 - p);
        dk[j] = __longlong_as_double((__double_as_longlong(1e10) & 0xFFFFFFFFFFFFE000ULL)
                                     | (unsigned long long)rid[j]);
    }
    __shared__ double swd[2][8];
    if (tid == 0) fidx[b * NS] = 0;
    double cx = (double)xb[0], cy = (double)xb[1], cz = (double)xb[2];
    for (int t = 1; t < NS; t++) {
        double wmax = 0.0;
#pragma unroll
        for (int j = 0; j < 16; j++) {
            double dx = px[j] - cx, dy = py[j] - cy, dz = pz[j] - cz;
            double d = fma(dx, dx, fma(dy, dy, dz * dz));
            unsigned long long kb = (__double_as_longlong(d) & 0xFFFFFFFFFFFFE000ULL)
                                  | (unsigned long long)rid[j];
            double nk = fmin(dk[j], __longlong_as_double(kb));
            dk[j] = nk;
            wmax = fmax(wmax, nk);
        }
#pragma unroll
        for (int off = 32; off; off >>= 1)
            wmax = fmax(wmax, __shfl_xor(wmax, off));
        if (lane == 0) swd[t & 1][w] = wmax;
        __syncthreads();
        double m0 = fmax(fmax(swd[t & 1][0], swd[t & 1][1]), fmax(swd[t & 1][2], swd[t & 1][3]));
        double m1 = fmax(fmax(swd[t & 1][4], swd[t & 1][5]), fmax(swd[t & 1][6], swd[t & 1][7]));
        double gm = fmax(m0, m1);
        int idx = 8191 - (int)((unsigned int)__double_as_longlong(gm) & 0x1FFFu);
        int sidx = __builtin_amdgcn_readfirstlane(idx);
        const float* cp = xb + sidx * 3;
        cx = (double)cp[0]; cy = (double)cp[1]; cz = (double)cp[2];
        if (tid == 0) fidx[b * NS + t] = sidx;
    }
}

// ---------------- brute-force kNN top-16, packed keys, 4-way ref split ----------------
// Block: 64 queries x 4 parts (part == wave). Each part scans 2048 refs keeping a
// sorted top-16 of packed keys in 16 scalar registers (no arrays -> no scratch).
#define KT2 1024
__global__ void __launch_bounds__(256) k_knn(const float* __restrict__ xin, const int* __restrict__ fidx,
                                             int* __restrict__ knn) {
    __shared__ double sxd[KT2], syd[KT2], szd[KT2];     // 24 KB
    __shared__ double mk[4][16][64];                     // 32 KB: [part][rank][query]
    int tid = threadIdx.x;
    int part = tid >> 6;
    int ql = tid & 63;
    int gq = blockIdx.x * 64 + ql;
    int b = gq >> 12;
    const float* xb = xin + (size_t)b * NPTS * 3;
    int qi = fidx[gq];
    double qx = (double)xb[qi * 3], qy = (double)xb[qi * 3 + 1], qz = (double)xb[qi * 3 + 2];
    double kd0 = DBL_MAX, kd1 = DBL_MAX, kd2 = DBL_MAX, kd3 = DBL_MAX,
           kd4 = DBL_MAX, kd5 = DBL_MAX, kd6 = DBL_MAX, kd7 = DBL_MAX,
           kd8 = DBL_MAX, kd9 = DBL_MAX, kd10 = DBL_MAX, kd11 = DBL_MAX,
           kd12 = DBL_MAX, kd13 = DBL_MAX, kd14 = DBL_MAX, kd15 = DBL_MAX;
    for (int tile = 0; tile < NPTS / KT2; tile++) {
        for (int m = tid; m < KT2; m += 256) {
            int gj = tile * KT2 + m;
            sxd[m] = (double)xb[gj * 3];
            syd[m] = (double)xb[gj * 3 + 1];
            szd[m] = (double)xb[gj * 3 + 2];
        }
        __syncthreads();
        int base = part * (KT2 / 4);
        for (int m = 0; m < KT2 / 4; m++) {
            int li = base + m;
            double dx = qx - sxd[li], dy = qy - syd[li], dz = qz - szd[li];
            double d = fma(dx, dx, fma(dy, dy, dz * dz));
            double key = __longlong_as_double(
                (__double_as_longlong(d) & 0xFFFFFFFFFFFFE000ULL)
                | (unsigned long long)(tile * KT2 + li));
            if (key < kd15) {
                // branchless sorted shift-insert (top-down uses pre-update neighbors)
                kd15 = fmax(kd14, fmin(kd15, key)); kd14 = fmax(kd13, fmin(kd14, key));
                kd13 = fmax(kd12, fmin(kd13, key)); kd12 = fmax(kd11, fmin(kd12, key));
                kd11 = fmax(kd10, fmin(kd11, key)); kd10 = fmax(kd9,  fmin(kd10, key));
                kd9  = fmax(kd8,  fmin(kd9,  key)); kd8  = fmax(kd7,  fmin(kd8,  key));
                kd7  = fmax(kd6,  fmin(kd7,  key)); kd6  = fmax(kd5,  fmin(kd6,  key));
                kd5  = fmax(kd4,  fmin(kd5,  key)); kd4  = fmax(kd3,  fmin(kd4,  key));
                kd3  = fmax(kd2,  fmin(kd3,  key)); kd2  = fmax(kd1,  fmin(kd2,  key));
                kd1  = fmax(kd0,  fmin(kd1,  key)); kd0  = fmin(kd0,  key);
            }
        }
        __syncthreads();
    }
    mk[part][0][ql] = kd0;  mk[part][1][ql] = kd1;  mk[part][2][ql] = kd2;  mk[part][3][ql] = kd3;
    mk[part][4][ql] = kd4;  mk[part][5][ql] = kd5;  mk[part][6][ql] = kd6;  mk[part][7][ql] = kd7;
    mk[part][8][ql] = kd8;  mk[part][9][ql] = kd9;  mk[part][10][ql] = kd10; mk[part][11][ql] = kd11;
    mk[part][12][ql] = kd12; mk[part][13][ql] = kd13; mk[part][14][ql] = kd14; mk[part][15][ql] = kd15;
    __syncthreads();
    if (tid < 64) {
        // 4-way merge of sorted lists; keys are globally unique (index in low bits)
        int i0 = 0, i1 = 0, i2 = 0, i3 = 0;
        double h0 = mk[0][0][tid], h1 = mk[1][0][tid], h2 = mk[2][0][tid], h3 = mk[3][0][tid];
        int* outp = knn + (size_t)(blockIdx.x * 64 + tid) * 16;
#pragma unroll
        for (int k = 0; k < 16; k++) {
            double mm = fmin(fmin(h0, h1), fmin(h2, h3));
            outp[k] = (int)(__double_as_longlong(mm) & 0x1FFFULL);
            if (mm == h0)      { i0++; h0 = (i0 < 16) ? mk[0][i0][tid] : DBL_MAX; }
            else if (mm == h1) { i1++; h1 = (i1 < 16) ? mk[1][i1][tid] : DBL_MAX; }
            else if (mm == h2) { i2++; h2 = (i2 < 16) ? mk[2][i2][tid] : DBL_MAX; }
            else               { i3++; h3 = (i3 < 16) ? mk[3][i3][tid] : DBL_MAX; }
        }
    }
}

// ---------------- gather + maxpool(67) + conv3 (wave per point) ----------------
__global__ void __launch_bounds__(256) k_group(const float* __restrict__ xin, const float* __restrict__ feat,
                                               const int* __restrict__ fidx, const int* __restrict__ knn,
                                               const float* __restrict__ W3, const float* __restrict__ b3,
                                               float* __restrict__ y3, float* __restrict__ stats) {
    __shared__ float W3s[OUTC * CATC];
    __shared__ float x67[4][68];
    __shared__ float lsum[64], lsq[64];
    int tid = threadIdx.x, w = tid >> 6, lane = tid & 63;
    for (int i = tid; i < OUTC * CATC; i += 256) W3s[i] = W3[i];
    if (tid < 64) { lsum[tid] = 0.f; lsq[tid] = 0.f; }
    __syncthreads();
    float psum = 0.f, psq = 0.f;
    int p0 = blockIdx.x * 64 + w * 16;
    for (int it = 0; it < 16; it++) {
        int p = p0 + it;
        int b = p >> 12;
        int myidx = knn[p * 16 + (lane & 15)];
        int nbk[16];
#pragma unroll
        for (int k = 0; k < 16; k++) nbk[k] = __shfl(myidx, k);
        float m = -FLT_MAX;
#pragma unroll
        for (int k = 0; k < 16; k++) m = fmaxf(m, feat[(size_t)(b * NPTS + nbk[k]) * OUTC + lane]);
        x67[w][3 + lane] = m;
        if (lane < 3) {
            int ci = fidx[p];
            float cc = xin[(size_t)(b * NPTS + ci) * 3 + lane];
            float mg = -FLT_MAX;
#pragma unroll
            for (int k = 0; k < 16; k++) mg = fmaxf(mg, xin[(size_t)(b * NPTS + nbk[k]) * 3 + lane] - cc);
            x67[w][lane] = mg;
        }
        __syncthreads();
        float acc = b3[lane];
#pragma unroll
        for (int c = 0; c < CATC; c++) acc = fmaf(W3s[lane * CATC + c], x67[w][c], acc);
        y3[(size_t)p * OUTC + lane] = acc;
        psum += acc; psq = fmaf(acc, acc, psq);
        __syncthreads();
    }
    atomicAdd(&lsum[lane], psum);
    atomicAdd(&lsq[lane], psq);
    __syncthreads();
    if (tid < 64) { atomicAdd(&stats[64 + tid], lsum[tid]); atomicAdd(&stats[128 + tid], lsq[tid]); }
}

// ---------------- BN2 finalize ----------------
__global__ void k_stats2(float* __restrict__ stats) {
    int c = threadIdx.x;  // 64
    float m = stats[64 + c] / (float)TOTAL_S;
    float var = stats[128 + c] / (float)TOTAL_S - m * m;
    stats[192 + c] = m;
    stats[256 + c] = rsqrtf(var + BN_EPS);
}

// ---------------- BN2 + ReLU in place on y3 ----------------
__global__ void k_bnrelu2(float* __restrict__ y3, const float* __restrict__ stats,
                          const float* __restrict__ g2, const float* __restrict__ be2) {
    int i = blockIdx.x * blockDim.x + threadIdx.x;
    int c = i & 63;
    float v = y3[i];
    v = fmaf((v - stats[192 + c]) * stats[256 + c], g2[c], be2[c]);
    y3[i] = fmaxf(v, 0.f);
}

// ---------------- final conv: out = y3' @ W4^T + b4 ----------------
__global__ void __launch_bounds__(256) k_last(const float* __restrict__ y3, const float* __restrict__ W4,
                                              const float* __restrict__ b4, float* __restrict__ out) {
    __shared__ float W4t[OUTC * OUTC];
    for (int i = threadIdx.x; i < OUTC * OUTC; i += 256) W4t[(i & 63) * 64 + (i >> 6)] = W4[i];
    __syncthreads();
    int t = blockIdx.x * 256 + threadIdx.x;
    int p = t >> 6, o = t & 63;
    const float* yp = y3 + (size_t)p * OUTC;
    float acc = b4[o];
#pragma unroll
    for (int c = 0; c < OUTC; c++) acc = fmaf(W4t[c * 64 + o], yp[c], acc);
    out[t] = acc;
}

extern "C" void kernel_launch(void* const* d_in, const int* in_sizes, int n_in,
                              void* d_out, int out_size, void* d_ws, size_t ws_size,
                              hipStream_t stream) {
    const float* xin = (const float*)d_in[0];
    const float* W1  = (const float*)d_in[1];
    const float* b1  = (const float*)d_in[2];
    const float* g1  = (const float*)d_in[3];
    const float* be1 = (const float*)d_in[4];
    const float* W2  = (const float*)d_in[5];
    const float* b2  = (const float*)d_in[6];
    const float* W3  = (const float*)d_in[7];
    const float* b3  = (const float*)d_in[8];
    const float* g2  = (const float*)d_in[9];
    const float* be2 = (const float*)d_in[10];
    const float* W4  = (const float*)d_in[11];
    const float* b4  = (const float*)d_in[12];
    float* out = (float*)d_out;

    float* ws = (float*)d_ws;
    float* t1   = ws;                                       // 32*32768   = 1,048,576 f
    float* feat = t1 + (size_t)MIDC * TOTAL_PTS;            // 32768*64   = 2,097,152 f
    int*   fidx = (int*)(feat + (size_t)TOTAL_PTS * OUTC);  // 16384 i
    int*   knn  = fidx + TOTAL_S;                           // 16384*16   = 262,144 i
    float* y3   = (float*)(knn + (size_t)TOTAL_S * 16);     // 16384*64   = 1,048,576 f
    float* stats = y3 + (size_t)TOTAL_S * OUTC;             // 320 f

    k_zero<<<1, 256, 0, stream>>>(stats);
    k_first<<<TOTAL_PTS / 256, 256, 0, stream>>>(xin, W1, b1, t1);
    k_stats1<<<MIDC, 256, 0, stream>>>(t1, stats);
    k_feat<<<TOTAL_PTS / 256, 256, 0, stream>>>(t1, stats, g1, be1, W2, b2, feat);
    k_fps<<<NB, 512, 0, stream>>>(xin, fidx);
    k_knn<<<TOTAL_S / 64, 256, 0, stream>>>(xin, fidx, knn);
    k_group<<<TOTAL_S / 64, 256, 0, stream>>>(xin, feat, fidx, knn, W3, b3, y3, stats);
    k_stats2<<<1, 64, 0, stream>>>(stats);
    k_bnrelu2<<<TOTAL_S * OUTC / 256, 256, 0, stream>>>(y3, stats, g2, be2);
    k_last<<<TOTAL_S * OUTC / 256, 256, 0, stream>>>(y3, W4, b4, out);
}